// Round 8
// baseline (753.870 us; speedup 1.0000x reference)
//
#include <hip/hip_runtime.h>
#include <math.h>

// CTC prefix beam search — fused single dispatch, no heaters.
//  blocks 1..T: per-frame log-softmax + stable top-10 -> d_ws, release flag, exit.
//  block 0 (1 wave): polls flags, preloads top-k to LDS, runs the 200-step scan.
//  Beam rows carry forwarded parent payload (pb,pnb,last) so the g1 candidate
//  has no dependent parent-row read on the critical path.

#define BB 10
#define KK 10
#define VV 29
#define TMAX 256
#define NEGF (-1e30f)
#define DUPF (-2e30f)
#define MAGICF 0x5CA7F00Du

__device__ __forceinline__ float lae(float a, float b) {
    float m = fmaxf(a, b);
    return m + log1pf(expf(fminf(a, b) - m));
}
__device__ __forceinline__ unsigned int ordf(float f) {
    unsigned int u = __float_as_uint(f);
    return (u & 0x80000000u) ? ~u : (u | 0x80000000u);
}

__device__ __forceinline__ void topk_frame(const float* __restrict__ logits,
                                           int blank, int t, float* __restrict__ o,
                                           int L) {
    float lp = (L < VV) ? logits[t * VV + L] : -INFINITY;
    float mx = lp;
    #pragma unroll
    for (int off = 32; off >= 1; off >>= 1) mx = fmaxf(mx, __shfl_xor(mx, off));
    float sm = (L < VV) ? expf(lp - mx) : 0.f;
    #pragma unroll
    for (int off = 32; off >= 1; off >>= 1) sm += __shfl_xor(sm, off);
    float lz = mx + logf(sm);
    int arank = 0;
    #pragma unroll
    for (int u = 0; u < VV; ++u) {
        float lu = __shfl(lp, u);
        arank += (lu > lp) || (lu == lp && u < L);   // tie -> lower index
    }
    bool win = (L < VV) && (arank < KK);
    if (win) { o[2 * arank] = __int_as_float(L); o[2 * arank + 1] = lp - lz; }
    unsigned long long bm = __ballot(win && (L == blank));
    if (bm) { if (L == blank) { o[20] = __int_as_float(arank); o[21] = lp - lz; } }
    else    { if (L == 0)     { o[20] = __int_as_float(-1);    o[21] = 0.f;     } }
}

__global__ __launch_bounds__(64) void fused_kernel(
        const float* __restrict__ logits, const int* __restrict__ blank_p,
        float* __restrict__ out, int T, float* __restrict__ tkbuf,
        unsigned int* fflags) {

    const int L = threadIdx.x;

    if (blockIdx.x != 0) {
        // ---- top-k producer, then exit
        const int t = blockIdx.x - 1;
        topk_frame(logits, blank_p[0], t, tkbuf + t * 24, L);
        __syncthreads();
        if (L == 0)
            __hip_atomic_store(&fflags[t], MAGICF, __ATOMIC_RELEASE,
                               __HIP_MEMORY_SCOPE_AGENT);
        return;
    }

    // ========================= scan block =========================
    __shared__ __align__(16) float tkl[TMAX * 24];
    __shared__ __align__(16) float bsrow[16][8];  // {pb,pnb,f2,len, ppb,ppnb,_,_}
    __shared__ __align__(16) int   dupsig[12];    // (nlast+16) | (npar+1)<<8
    __shared__ __align__(16) unsigned long long kbuf[112];
    __shared__ unsigned short hist[TMAX][BB];
    __shared__ signed char pout[BB][TMAX];

    // init beam rows while producers work
    if (L < BB) {
        int last0 = (L == 0) ? -1 : -(L + 2);     // empty=slot0, sentinels 1..9
        int par0  = (L == 0) ? -1 : 0;            // sentinels' parent = empty
        int f2 = (last0 + 16) | ((par0 + 1) << 8) | ((-1 + 16) << 16);
        *(float4*)&bsrow[L][0] = make_float4((L == 0) ? 0.f : NEGF, NEGF,
                                             __int_as_float(f2), __int_as_float(0));
        *(float4*)&bsrow[L][4] = make_float4(0.f, NEGF, 0.f, 0.f);  // parent=empty
        dupsig[L] = f2 & 0xFFFF;
    } else if (L < 12) dupsig[L] = 0;
    if (L < 2) kbuf[110 + L] = 0ull;

    // wait for all frames' top-k (poison 0xAA != MAGIC, no init needed)
    for (;;) {
        bool ok = true;
        for (int base = 0; base < T; base += 64) {
            int idx = base + L;
            unsigned f = (idx < T)
                ? __hip_atomic_load(&fflags[idx], __ATOMIC_RELAXED,
                                    __HIP_MEMORY_SCOPE_AGENT)
                : MAGICF;
            ok = ok && (f == MAGICF);
        }
        if (__all(ok)) break;
    }
    __builtin_amdgcn_fence(__ATOMIC_ACQUIRE, "agent");

    // preload all frames' top-k into LDS
    {
        int n4 = (T * 24) >> 2;
        const float4* g4 = (const float4*)tkbuf;
        float4* l4 = (float4*)tkl;
        for (int i = L; i < n4; i += 64) l4[i] = g4[i];
    }
    __syncthreads();

    // static candidate->lane mapping: c0 = L (g1 if L<10 else g2), c1 = 64+L (g2)
    const int b0 = (L < BB) ? L : (L - 10) / 10;
    const int k0 = (L < BB) ? 0 : (L - 10) % 10;
    const bool has1 = (L < 46);
    const int b1 = (54 + L) / 10, k1 = (54 + L) % 10;
    const int blank = blank_p[0];

    // frame register prefetch for t=0
    float4 fw0, fw1, fw2, fw3, fw4, fw5; float2 fp0, fp1;
    {
        const float4* tp = (const float4*)&tkl[0];
        fw0 = tp[0]; fw1 = tp[1]; fw2 = tp[2]; fw3 = tp[3]; fw4 = tp[4]; fw5 = tp[5];
        fp0 = *(const float2*)&tkl[2 * k0];
        fp1 = *(const float2*)&tkl[2 * k1];
    }

    for (int t = 0; t < T; ++t) {
        int symi[KK] = {__float_as_int(fw0.x), __float_as_int(fw0.z),
                        __float_as_int(fw1.x), __float_as_int(fw1.z),
                        __float_as_int(fw2.x), __float_as_int(fw2.z),
                        __float_as_int(fw3.x), __float_as_int(fw3.z),
                        __float_as_int(fw4.x), __float_as_int(fw4.z)};
        float pks[KK] = {fw0.y, fw0.w, fw1.y, fw1.w, fw2.y, fw2.w,
                         fw3.y, fw3.w, fw4.y, fw4.w};
        int bk = __float_as_int(fw5.x);
        float pbl = fw5.y;
        float2 pr0 = fp0, pr1 = fp1;

        // start-of-step independent state reads (ordered after prev commit barrier)
        float4 rowA = *(const float4*)&bsrow[b0][0];
        float4 rowB = *(const float4*)&bsrow[b0][4];   // forwarded parent data
        float4 row1 = *(const float4*)&bsrow[b1][0];
        int4 dg0 = *(const int4*)&dupsig[0];
        int4 dg1 = *(const int4*)&dupsig[4];
        int2 dg2 = *(const int2*)&dupsig[8];
        int sig[BB] = {dg0.x, dg0.y, dg0.z, dg0.w, dg1.x, dg1.y, dg1.z, dg1.w,
                       dg2.x, dg2.y};

        // ---- candidates
        float tot0, pay_pb = NEGF, pay_pnb = NEGF;
        int nlen0, nlast0, x0, tok0;
        if (L < BB) {
            // g1: unchanged(b0); merges with extend(parent, last) — parent data
            // forwarded in rowB, no dependent LDS read.
            float pb_b = rowA.x, pnb_b = rowA.y;
            int f2 = __float_as_int(rowA.z);
            int last_b = (f2 & 255) - 16;
            int par_b  = ((f2 >> 8) & 255) - 1;
            int last_p = ((f2 >> 16) & 255) - 16;
            nlen0 = __float_as_int(rowA.w);
            nlast0 = last_b; x0 = par_b; tok0 = -1;
            int kl = -1; float pkl = 0.f;
            #pragma unroll
            for (int k = 0; k < KK; ++k)
                if (symi[k] == last_b) { kl = k; pkl = pks[k]; }
            if (bk >= 0) pay_pb = lae(pb_b + pbl, pnb_b + pbl);
            if (kl >= 0) {
                float a = pnb_b + pkl;                    // g1 member (lower index)
                if (par_b >= 0) {
                    float e = (last_b == last_p) ? (rowB.x + pkl)
                               : lae(rowB.x + pkl, rowB.y + pkl);
                    float mxx = fmaxf(a, e);
                    pay_pnb = mxx + logf(expf(a - mxx) + expf(e - mxx));
                } else pay_pnb = a;
            }
            tot0 = lae(pay_pb, pay_pnb);
        } else {
            // g2: extend(b0, s)
            int s = __float_as_int(pr0.x); float p = pr0.y;
            int last_b = (__float_as_int(rowA.z) & 255) - 16;
            nlen0 = __float_as_int(rowA.w) + 1;
            nlast0 = s; x0 = b0; tok0 = s;
            int target = ((b0 + 1) << 8) | (s + 16);
            bool dup = false;
            #pragma unroll
            for (int i = 0; i < BB; ++i) dup = dup || (sig[i] == target);
            float v;
            if (s == blank)        v = NEGF;
            else if (s == last_b)  v = rowA.x + p;
            else                   v = lae(rowA.x + p, rowA.y + p);
            pay_pnb = v;
            tot0 = dup ? DUPF : v;       // lae(NEGF,v) == v bitwise in f32
        }
        // c1 (g2) for lanes 0..45
        float v1 = NEGF, tot1 = -INFINITY; int nlen1 = 0, s1i = 0;
        if (has1) {
            int s = __float_as_int(pr1.x); float p = pr1.y;
            int last_b = (__float_as_int(row1.z) & 255) - 16;
            nlen1 = __float_as_int(row1.w) + 1;
            s1i = s;
            int target = ((b1 + 1) << 8) | (s + 16);
            bool dup = false;
            #pragma unroll
            for (int i = 0; i < BB; ++i) dup = dup || (sig[i] == target);
            if (s == blank)        v1 = NEGF;
            else if (s == last_b)  v1 = row1.x + p;
            else                   v1 = lae(row1.x + p, row1.y + p);
            tot1 = dup ? DUPF : v1;
        }

        unsigned long long key0 = (((unsigned long long)ordf(tot0)) << 32) | (unsigned)(127 - L);
        unsigned long long key1 = (((unsigned long long)ordf(tot1)) << 32) | (unsigned)(127 - (64 + L));
        kbuf[L] = key0;
        if (has1) kbuf[64 + L] = key1;
        __syncthreads();                                   // S1: keys visible

        // prefetch next frame into registers (independent of rank)
        {
            int tn = (t + 1 < T) ? (t + 1) : t;
            const float4* tp = (const float4*)&tkl[tn * 24];
            fw0 = tp[0]; fw1 = tp[1]; fw2 = tp[2]; fw3 = tp[3]; fw4 = tp[4]; fw5 = tp[5];
            fp0 = *(const float2*)&tkl[tn * 24 + 2 * k0];
            fp1 = *(const float2*)&tkl[tn * 24 + 2 * k1];
        }

        // ---- exact rank (value desc, index asc) vs all 112 keys
        int r0 = 0, r1c = 0;
        const ulonglong2* k2 = (const ulonglong2*)kbuf;
        #pragma unroll
        for (int q = 0; q < 56; ++q) {
            ulonglong2 w = k2[q];
            r0  += (w.x > key0) + (w.y > key0);
            r1c += (w.x > key1) + (w.y > key1);
        }

        // parent remap + parent payload fetch — one shuffle window.
        // parent old slot for c0 is x0 (g1: old par; g2: b0); for c1 it's b1.
        int g1r = (L < BB && r0 < BB) ? r0 : -1;
        int xs0 = (x0 < 0) ? 0 : x0;
        int   nparA  = __shfl(g1r, xs0);  if (x0 < 0) nparA = -1;
        float ppbA   = __shfl(pay_pb, xs0);
        float ppnbA  = __shfl(pay_pnb, xs0);
        int   plastA = __shfl(nlast0, xs0);
        int   nparB  = __shfl(g1r, b1);
        float ppbB   = __shfl(pay_pb, b1);
        float ppnbB  = __shfl(pay_pnb, b1);
        int   plastB = __shfl(nlast0, b1);

        // ---- winner writes (direct commit)
        if (r0 < BB) {
            int f2n = (nlast0 + 16) | ((nparA + 1) << 8) | ((plastA + 16) << 16);
            float wpb = (L < BB) ? pay_pb : NEGF;
            *(float4*)&bsrow[r0][0] = make_float4(wpb, pay_pnb,
                                                  __int_as_float(f2n),
                                                  __int_as_float(nlen0));
            *(float4*)&bsrow[r0][4] = make_float4(ppbA, ppnbA, 0.f, 0.f);
            dupsig[r0] = f2n & 0xFFFF;
            hist[t][r0] = (unsigned short)(b0 | ((tok0 + 1) << 8));
        }
        if (has1 && r1c < BB) {
            int f2n = (s1i + 16) | ((nparB + 1) << 8) | ((plastB + 16) << 16);
            *(float4*)&bsrow[r1c][0] = make_float4(NEGF, v1,
                                                   __int_as_float(f2n),
                                                   __int_as_float(nlen1));
            *(float4*)&bsrow[r1c][4] = make_float4(ppbB, ppnbB, 0.f, 0.f);
            dupsig[r1c] = f2n & 0xFFFF;
            hist[t][r1c] = (unsigned short)(b1 | ((s1i + 1) << 8));
        }
        __syncthreads();                                   // S2: state committed
    }

    // ---- outputs: [scores(B) | prefixes(B*T) | lengths(B)] as f32
    int mylen = 0;
    if (L < BB) {
        float4 rj = *(const float4*)&bsrow[L][0];
        mylen = __float_as_int(rj.w);
        out[L] = lae(rj.x, rj.y);
        out[BB + BB * T + L] = (float)mylen;
    }
    for (int i = L; i < BB * TMAX; i += 64) (&pout[0][0])[i] = -1;
    __syncthreads();
    if (L < BB) {
        int cur = L, pos = mylen - 1;
        for (int tt = T - 1; tt >= 0; --tt) {
            unsigned short h = hist[tt][cur];
            int tok = (h >> 8) - 1;
            if (tok >= 0) pout[L][pos--] = (signed char)tok;
            cur = h & 255;
        }
        if (mylen == 0 && cur > 0) pout[L][0] = (signed char)(-(cur + 2));  // guard
    }
    __syncthreads();
    for (int e = L; e < BB * T; e += 64) {
        int j = e / T, p = e - j * T;
        out[BB + e] = (float)pout[j][p];
    }
}

// fallback producer (only used if ws is too small for flags — then we run
// producers in a prior dispatch and scan with flags pre-set)
__global__ __launch_bounds__(64) void topk_only(const float* __restrict__ logits,
                                                const int* __restrict__ blank_p,
                                                float* __restrict__ tkbuf,
                                                unsigned int* fflags) {
    const int t = blockIdx.x;
    topk_frame(logits, blank_p[0], t, tkbuf + t * 24, threadIdx.x);
    __syncthreads();
    if (threadIdx.x == 0)
        __hip_atomic_store(&fflags[t], MAGICF, __ATOMIC_RELEASE,
                           __HIP_MEMORY_SCOPE_AGENT);
}

extern "C" void kernel_launch(void* const* d_in, const int* in_sizes, int n_in,
                              void* d_out, int out_size, void* d_ws, size_t ws_size,
                              hipStream_t stream) {
    const float* logits = (const float*)d_in[0];
    const int* blank_p = (const int*)d_in[2];
    int T = in_sizes[0] / VV;   // 200
    float* tkbuf = (float*)d_ws;                               // T*24 floats

    size_t ff_off = ((size_t)T * 24 * 4 + 255) & ~(size_t)255; // frame flags
    size_t need = ff_off + (size_t)T * 4;
    unsigned int* fflags = (unsigned int*)((char*)d_ws + ff_off);

    if (ws_size >= need) {
        fused_kernel<<<dim3(1 + T), dim3(64), 0, stream>>>(
            logits, blank_p, (float*)d_out, T, tkbuf, fflags);
    } else {
        // should not happen with the provided workspace; safe sequential path
        topk_only<<<dim3(T), dim3(64), 0, stream>>>(logits, blank_p, tkbuf, fflags);
        fused_kernel<<<dim3(1), dim3(64), 0, stream>>>(
            logits, blank_p, (float*)d_out, T, tkbuf, fflags);
    }
}

// Round 9
// 550.798 us; speedup vs baseline: 1.3687x; 1.3687x over previous
//
#include <hip/hip_runtime.h>
#include <math.h>

// CTC prefix beam search — fused single dispatch.
//  blocks 1..T: per-frame log-softmax + stable top-10 (wave0 only) -> d_ws.
//  block 0 (2 waves, 128 threads): ONE candidate per lane (110 candidates),
//  rank = 112 compares/lane, candidate phases split across two SIMDs.

#define BB 10
#define KK 10
#define VV 29
#define TMAX 256
#define NEGF (-1e30f)
#define DUPF (-2e30f)
#define MAGICF 0x5CA7F00Du

__device__ __forceinline__ float lae(float a, float b) {
    float m = fmaxf(a, b);
    return m + log1pf(expf(fminf(a, b) - m));
}
__device__ __forceinline__ unsigned int ordf(float f) {
    unsigned int u = __float_as_uint(f);
    return (u & 0x80000000u) ? ~u : (u | 0x80000000u);
}

__device__ __forceinline__ void topk_frame(const float* __restrict__ logits,
                                           int blank, int t, float* __restrict__ o,
                                           int L) {
    float lp = (L < VV) ? logits[t * VV + L] : -INFINITY;
    float mx = lp;
    #pragma unroll
    for (int off = 32; off >= 1; off >>= 1) mx = fmaxf(mx, __shfl_xor(mx, off));
    float sm = (L < VV) ? expf(lp - mx) : 0.f;
    #pragma unroll
    for (int off = 32; off >= 1; off >>= 1) sm += __shfl_xor(sm, off);
    float lz = mx + logf(sm);
    int arank = 0;
    #pragma unroll
    for (int u = 0; u < VV; ++u) {
        float lu = __shfl(lp, u);
        arank += (lu > lp) || (lu == lp && u < L);   // tie -> lower index
    }
    bool win = (L < VV) && (arank < KK);
    if (win) { o[2 * arank] = __int_as_float(L); o[2 * arank + 1] = lp - lz; }
    unsigned long long bm = __ballot(win && (L == blank));
    if (bm) { if (L == blank) { o[20] = __int_as_float(arank); o[21] = lp - lz; } }
    else    { if (L == 0)     { o[20] = __int_as_float(-1);    o[21] = 0.f;     } }
}

__global__ __launch_bounds__(128) void fused_kernel(
        const float* __restrict__ logits, const int* __restrict__ blank_p,
        float* __restrict__ out, int T, float* __restrict__ tkbuf,
        unsigned int* fflags) {

    const int L = threadIdx.x;

    if (blockIdx.x != 0) {
        // ---- top-k producer (wave0 does the math), then exit
        const int t = blockIdx.x - 1;
        if (L < 64) topk_frame(logits, blank_p[0], t, tkbuf + t * 24, L);
        __syncthreads();
        if (L == 0)
            __hip_atomic_store(&fflags[t], MAGICF, __ATOMIC_RELEASE,
                               __HIP_MEMORY_SCOPE_AGENT);
        return;
    }

    // ========================= scan block (2 waves) =========================
    __shared__ __align__(16) float tkl[TMAX * 24];
    __shared__ __align__(16) float bsrow[16][8];  // {pb,pnb,f2,len, ppb,ppnb,_,_}
    __shared__ __align__(16) int   dupsig[12];    // (last+16) | (par+1)<<8
    __shared__ __align__(16) unsigned long long kbuf[128];
    __shared__ __align__(16) float4 aux4[12];     // {pay_pb,pay_pnb,g1r,nlast} lanes 0-9
    __shared__ unsigned short hist[TMAX][BB];
    __shared__ signed char pout[BB][TMAX];

    // init beam rows
    if (L < BB) {
        int last0 = (L == 0) ? -1 : -(L + 2);     // empty=slot0, sentinels 1..9
        int par0  = (L == 0) ? -1 : 0;            // sentinels' parent = empty
        int f2 = (last0 + 16) | ((par0 + 1) << 8) | ((-1 + 16) << 16);
        *(float4*)&bsrow[L][0] = make_float4((L == 0) ? 0.f : NEGF, NEGF,
                                             __int_as_float(f2), __int_as_float(0));
        *(float4*)&bsrow[L][4] = make_float4(0.f, NEGF, 0.f, 0.f);  // parent=empty
        dupsig[L] = f2 & 0xFFFF;
    } else if (L < 12) dupsig[L] = 0;
    if (L >= 110 && L < 112) kbuf[L] = 0ull;      // rank-loop pad, never overwritten

    // wait for all frames' top-k (wave0 polls; wave1 parks at the barrier)
    if (L < 64) {
        for (;;) {
            bool ok = true;
            for (int base = 0; base < T; base += 64) {
                int idx = base + L;
                unsigned f = (idx < T)
                    ? __hip_atomic_load(&fflags[idx], __ATOMIC_RELAXED,
                                        __HIP_MEMORY_SCOPE_AGENT)
                    : MAGICF;
                ok = ok && (f == MAGICF);
            }
            if (__all(ok)) break;
        }
    }
    __syncthreads();
    __builtin_amdgcn_fence(__ATOMIC_ACQUIRE, "agent");

    // preload all frames' top-k into LDS
    {
        int n4 = (T * 24) >> 2;
        const float4* g4 = (const float4*)tkbuf;
        float4* l4 = (float4*)tkl;
        for (int i = L; i < n4; i += 128) l4[i] = g4[i];
    }
    __syncthreads();

    // one candidate per lane: c = L; c<10 -> g1(c); 10<=c<110 -> g2(b,k)
    const int c = L;
    const bool active = c < BB + BB * KK;         // 110
    const bool isg1 = c < BB;
    const int b = isg1 ? c : (c - 10) / 10;
    const int k = isg1 ? 0 : (c - 10) % 10;
    const int blank = blank_p[0];

    for (int t = 0; t < T; ++t) {
        const float* tk = &tkl[t * 24];
        float tot = -INFINITY, pay_pb = NEGF, pay_pnb = NEGF;
        int nlen = 0, nlast = 0, xsl = -1, tok = -1;

        if (active) {
            float4 rowA = *(const float4*)&bsrow[b][0];
            int f2 = __float_as_int(rowA.z);
            int last_b = (f2 & 255) - 16;
            if (isg1) {
                // g1: unchanged(b); merges with extend(parent, last)
                float4 rowB = *(const float4*)&bsrow[b][4];   // forwarded parent
                int par_b  = ((f2 >> 8) & 255) - 1;
                int last_p = ((f2 >> 16) & 255) - 16;
                nlen = __float_as_int(rowA.w);
                nlast = last_b; xsl = par_b; tok = -1;
                const float4* tp = (const float4*)tk;
                float4 w0 = tp[0], w1 = tp[1], w2 = tp[2], w3 = tp[3], w4 = tp[4];
                float2 w5 = *(const float2*)&tk[20];
                int symi[KK] = {__float_as_int(w0.x), __float_as_int(w0.z),
                                __float_as_int(w1.x), __float_as_int(w1.z),
                                __float_as_int(w2.x), __float_as_int(w2.z),
                                __float_as_int(w3.x), __float_as_int(w3.z),
                                __float_as_int(w4.x), __float_as_int(w4.z)};
                float pks[KK] = {w0.y, w0.w, w1.y, w1.w, w2.y, w2.w,
                                 w3.y, w3.w, w4.y, w4.w};
                int bk = __float_as_int(w5.x);
                float pbl = w5.y;
                int kl = -1; float pkl = 0.f;
                #pragma unroll
                for (int kk = 0; kk < KK; ++kk)
                    if (symi[kk] == last_b) { kl = kk; pkl = pks[kk]; }
                if (bk >= 0) pay_pb = lae(rowA.x + pbl, rowA.y + pbl);
                if (kl >= 0) {
                    float a = rowA.y + pkl;                   // g1 member (lower idx)
                    if (par_b >= 0) {
                        float e = (last_b == last_p) ? (rowB.x + pkl)
                                   : lae(rowB.x + pkl, rowB.y + pkl);
                        float mxx = fmaxf(a, e);
                        pay_pnb = mxx + logf(expf(a - mxx) + expf(e - mxx));
                    } else pay_pnb = a;
                }
                tot = lae(pay_pb, pay_pnb);
            } else {
                // g2: extend(b, s)
                float2 pr = *(const float2*)&tk[2 * k];
                int s = __float_as_int(pr.x); float p = pr.y;
                nlen = __float_as_int(rowA.w) + 1;
                nlast = s; xsl = b; tok = s;
                int4 dg0 = *(const int4*)&dupsig[0];
                int4 dg1 = *(const int4*)&dupsig[4];
                int2 dg2 = *(const int2*)&dupsig[8];
                int sig[BB] = {dg0.x, dg0.y, dg0.z, dg0.w,
                               dg1.x, dg1.y, dg1.z, dg1.w, dg2.x, dg2.y};
                int target = ((b + 1) << 8) | (s + 16);
                bool dup = false;
                #pragma unroll
                for (int i = 0; i < BB; ++i) dup = dup || (sig[i] == target);
                float v;
                if (s == blank)        v = NEGF;
                else if (s == last_b)  v = rowA.x + p;
                else                   v = lae(rowA.x + p, rowA.y + p);
                pay_pnb = v;
                tot = dup ? DUPF : v;        // lae(NEGF,v) == v bitwise in f32
            }
        }

        unsigned long long key =
            (((unsigned long long)ordf(tot)) << 32) | (unsigned)(127 - c);
        if (active) kbuf[c] = key;
        __syncthreads();                                   // B1: keys visible

        // exact rank (value desc, index asc) of own candidate vs all 112 keys
        int r = 0;
        const ulonglong2* k2 = (const ulonglong2*)kbuf;
        #pragma unroll
        for (int q = 0; q < 56; ++q) {
            ulonglong2 w = k2[q];
            r += (w.x > key) + (w.y > key);
        }
        bool winner = active && (r < BB);
        if (winner) {
            *(float2*)&bsrow[r][0] = make_float2(isg1 ? pay_pb : NEGF, pay_pnb);
            bsrow[r][3] = __int_as_float(nlen);
            hist[t][r] = (unsigned short)(b | ((tok + 1) << 8));
        }
        if (L < BB)
            aux4[L] = make_float4(pay_pb, pay_pnb,
                                  __int_as_float((r < BB) ? r : -1),
                                  __int_as_float(nlast));
        __syncthreads();                                   // B2: aux + rows(0,1,3)

        if (winner) {
            // parent old slot: g1 -> old par; g2 -> b. New slot via aux.
            int npar = -1, plast = -1; float ppb = 0.f, ppnb = NEGF;
            if (xsl >= 0) {
                float4 ax = aux4[xsl];
                npar  = __float_as_int(ax.z);
                plast = __float_as_int(ax.w);
                ppb = ax.x; ppnb = ax.y;
            }
            int f2n = (nlast + 16) | ((npar + 1) << 8) | ((plast + 16) << 16);
            bsrow[r][2] = __int_as_float(f2n);
            *(float2*)&bsrow[r][4] = make_float2(ppb, ppnb);
            dupsig[r] = f2n & 0xFFFF;
        }
        __syncthreads();                                   // B3: state committed
    }

    // ---- outputs: [scores(B) | prefixes(B*T) | lengths(B)] as f32
    int mylen = 0;
    if (L < BB) {
        float4 rj = *(const float4*)&bsrow[L][0];
        mylen = __float_as_int(rj.w);
        out[L] = lae(rj.x, rj.y);
        out[BB + BB * T + L] = (float)mylen;
    }
    for (int i = L; i < BB * TMAX; i += 128) (&pout[0][0])[i] = -1;
    __syncthreads();
    if (L < BB) {
        int cur = L, pos = mylen - 1;
        for (int tt = T - 1; tt >= 0; --tt) {
            unsigned short h = hist[tt][cur];
            int tk2 = (h >> 8) - 1;
            if (tk2 >= 0) pout[L][pos--] = (signed char)tk2;
            cur = h & 255;
        }
        if (mylen == 0 && cur > 0) pout[L][0] = (signed char)(-(cur + 2));  // guard
    }
    __syncthreads();
    for (int e = L; e < BB * T; e += 128) {
        int j = e / T, p = e - j * T;
        out[BB + e] = (float)pout[j][p];
    }
}

extern "C" void kernel_launch(void* const* d_in, const int* in_sizes, int n_in,
                              void* d_out, int out_size, void* d_ws, size_t ws_size,
                              hipStream_t stream) {
    const float* logits = (const float*)d_in[0];
    const int* blank_p = (const int*)d_in[2];
    int T = in_sizes[0] / VV;   // 200
    float* tkbuf = (float*)d_ws;                               // T*24 floats

    size_t ff_off = ((size_t)T * 24 * 4 + 255) & ~(size_t)255; // frame flags
    unsigned int* fflags = (unsigned int*)((char*)d_ws + ff_off);

    fused_kernel<<<dim3(1 + T), dim3(128), 0, stream>>>(
        logits, blank_p, (float*)d_out, T, tkbuf, fflags);
}